// Round 2
// baseline (10864.359 us; speedup 1.0000x reference)
//
#include <hip/hip_runtime.h>

#define BB 8
#define NN 2048
#define WGS 1024
#define GRID 256
#define WG_PER_B (GRID / BB)                 // 32 WGs per batch
#define ROWS_PER_WG (NN / WG_PER_B)          // 64
#define NWAVES (WGS / 64)                    // 16
#define ROWS_PER_WAVE (ROWS_PER_WG / NWAVES) // 4
#define CHUNKS (NN / 64)                     // 32
#define MAX_ITER 50

// eps = 0.005; work in log2 domain: SCL = log2(e)/eps
constexpr float SCL       = 288.5390081777927f;
constexpr float LN2f      = 0.6931471805599453f;
constexpr float EPSf      = 0.005f;
constexpr float EPS_LOGMU = -0.03812309493079699f; // 0.005 * (-ln 2048)

#define DEV_SCOPE __HIP_MEMORY_SCOPE_AGENT

// Relaxed agent-scope atomics: L2-bypassing (sc1) ops served at the coherence
// point. No acquire/release -> no buffer_inv/buffer_wbl2 cache maintenance.
__device__ __forceinline__ float aloadf(const float* p) {
  return __hip_atomic_load(p, __ATOMIC_RELAXED, DEV_SCOPE);
}
__device__ __forceinline__ void astoref(float* p, float v) {
  __hip_atomic_store(p, v, __ATOMIC_RELAXED, DEV_SCOPE);
}

__device__ __forceinline__ float wmax(float v) {
  #pragma unroll
  for (int d = 32; d; d >>= 1) v = fmaxf(v, __shfl_xor(v, d, 64));
  return v;
}
__device__ __forceinline__ float wsum(float v) {
  #pragma unroll
  for (int d = 32; d; d >>= 1) v += __shfl_xor(v, d, 64);
  return v;
}

// Sense-reversing barrier over nwg workgroups using relaxed agent atomics.
// Ordering: each wave's pre-s_barrier s_waitcnt vmcnt(0) guarantees its sc1
// stores reached the coherence point before tid0 arrives; the releaser orders
// cnt-reset before gen-flip with an explicit vmcnt(0).
__device__ __forceinline__ void coopBarrier(int* cnt, int* gen, int nwg) {
  __syncthreads();
  if (threadIdx.x == 0) {
    asm volatile("s_waitcnt vmcnt(0)" ::: "memory");
    int g = __hip_atomic_load(gen, __ATOMIC_RELAXED, DEV_SCOPE);
    int old = __hip_atomic_fetch_add(cnt, 1, __ATOMIC_RELAXED, DEV_SCOPE);
    if (old == nwg - 1) {
      __hip_atomic_store(cnt, 0, __ATOMIC_RELAXED, DEV_SCOPE);
      asm volatile("s_waitcnt vmcnt(0)" ::: "memory");
      __hip_atomic_store(gen, g + 1, __ATOMIC_RELAXED, DEV_SCOPE);
    } else {
      while (__hip_atomic_load(gen, __ATOMIC_RELAXED, DEV_SCOPE) == g)
        __builtin_amdgcn_s_sleep(8);
    }
  }
  __syncthreads();
}

// One wave computes 2 potential rows per pass over JA (q loaded once per 2 rows).
// JA[j] = {x,y,z,A_j}, A_j = (pot_j - |q_j|^2)*SCL (log2 units).
// T_ij = A_j + (2s p_i)·q_j ; row const B_i = -|p_i|^2 s folded into the LSE.
__device__ __forceinline__ void potentialRows(
    const float4* __restrict__ JA, const float4* __restrict__ JOwn,
    float* __restrict__ outPot, int rowbase, int wv, int lane)
{
  #pragma unroll 1
  for (int rg = 0; rg < ROWS_PER_WAVE / 2; ++rg) {
    const int i0 = rowbase + wv * ROWS_PER_WAVE + rg * 2;
    const int i1 = i0 + 1;
    float4 p0 = JOwn[i0];                       // broadcast LDS reads
    float4 p1 = JOwn[i1];
    float pp0 = fmaf(p0.x, p0.x, fmaf(p0.y, p0.y, p0.z * p0.z));
    float pp1 = fmaf(p1.x, p1.x, fmaf(p1.y, p1.y, p1.z * p1.z));
    float X0x = 2.f * SCL * p0.x, X0y = 2.f * SCL * p0.y, X0z = 2.f * SCL * p0.z;
    float X1x = 2.f * SCL * p1.x, X1y = 2.f * SCL * p1.y, X1z = 2.f * SCL * p1.z;
    float B0 = -pp0 * SCL, B1 = -pp1 * SCL;
    float t0[CHUNKS], t1[CHUNKS];
    float m0a = -3.4e38f, m0b = -3.4e38f, m1a = -3.4e38f, m1b = -3.4e38f;
    #pragma unroll
    for (int k = 0; k < CHUNKS; ++k) {
      float4 q = JA[k * 64 + lane];
      float T0 = fmaf(X0x, q.x, fmaf(X0y, q.y, fmaf(X0z, q.z, q.w)));
      float T1 = fmaf(X1x, q.x, fmaf(X1y, q.y, fmaf(X1z, q.z, q.w)));
      t0[k] = T0; t1[k] = T1;
      if (k & 1) { m0b = fmaxf(m0b, T0); m1b = fmaxf(m1b, T1); }
      else       { m0a = fmaxf(m0a, T0); m1a = fmaxf(m1a, T1); }
    }
    float M0 = wmax(fmaxf(m0a, m0b));
    float M1 = wmax(fmaxf(m1a, m1b));
    float s0a = 0.f, s0b = 0.f, s1a = 0.f, s1b = 0.f;
    #pragma unroll
    for (int k = 0; k < CHUNKS; ++k) {
      if (k & 1) { s0b += exp2f(t0[k] - M0); s1b += exp2f(t1[k] - M1); }
      else       { s0a += exp2f(t0[k] - M0); s1a += exp2f(t1[k] - M1); }
    }
    float S0 = wsum(s0a + s0b);
    float S1 = wsum(s1a + s1b);
    if (lane == 0) {
      astoref(&outPot[i0], EPS_LOGMU - EPSf * LN2f * (B0 + M0 + log2f(S0)));
      astoref(&outPot[i1], EPS_LOGMU - EPSf * LN2f * (B1 + M1 + log2f(S1)));
    }
  }
}

__global__ __launch_bounds__(WGS, 4) void emd_sinkhorn(
    const float* __restrict__ pcs1, const float* __restrict__ pcs2,
    float* __restrict__ out, float* __restrict__ ws)
{
  __shared__ float4 J1[NN];
  __shared__ float4 J2[NN];
  __shared__ float redbuf[NWAVES];

  const int wg = blockIdx.x, tid = threadIdx.x;
  const int b = wg / WG_PER_B, sub = wg % WG_PER_B;
  const int rowbase = sub * ROWS_PER_WG;
  const int lane = tid & 63, wv = tid >> 6;

  float* fArr = ws;
  float* gArr = ws + BB * NN;
  int*   ctrl = (int*)(ws + 2 * BB * NN);      // zeroed by host memset
  float* accum = (float*)&ctrl[0];             // own 64B line
  int* bcnt = &ctrl[16 + b * 32];              // per-batch counter line
  int* bgen = bcnt + 16;                       // per-batch gen line
  int* gcnt = &ctrl[16 + BB * 32];             // global barrier
  int* ggen = gcnt + 16;

  const float* p1 = pcs1 + (size_t)b * NN * 3;
  const float* p2 = pcs2 + (size_t)b * NN * 3;
  float* myF = fArr + b * NN;
  float* myG = gArr + b * NN;

  for (int i = tid; i < NN; i += WGS) {
    J1[i] = make_float4(p1[3 * i], p1[3 * i + 1], p1[3 * i + 2], 0.f);
    J2[i] = make_float4(p2[3 * i], p2[3 * i + 1], p2[3 * i + 2], 0.f);
  }
  __syncthreads();

  for (int it = 0; it < MAX_ITER; ++it) {
    // ---- f-update: stage A_j = (g_j - |q|^2)*SCL into J2.w
    for (int j = tid; j < NN; j += WGS) {
      float4 q = J2[j];
      float qq = fmaf(q.x, q.x, fmaf(q.y, q.y, q.z * q.z));
      float gj = (it == 0) ? 0.f : aloadf(&myG[j]);
      J2[j].w = (gj - qq) * SCL;
    }
    __syncthreads();
    potentialRows(J2, J1, myF, rowbase, wv, lane);
    coopBarrier(bcnt, bgen, WG_PER_B);         // f complete, batch-wide

    // ---- g-update: stage A_i = (f_i - |p|^2)*SCL into J1.w
    for (int i = tid; i < NN; i += WGS) {
      float4 p = J1[i];
      float pp = fmaf(p.x, p.x, fmaf(p.y, p.y, p.z * p.z));
      J1[i].w = (aloadf(&myF[i]) - pp) * SCL;
    }
    __syncthreads();
    potentialRows(J1, J2, myG, rowbase, wv, lane);
    coopBarrier(bcnt, bgen, WG_PER_B);         // g complete
  }

  // ---- final: dist_i = N * sum_j exp2((f_i+g_j-C_ij)*SCL) * C_ij
  for (int j = tid; j < NN; j += WGS) J2[j].w = aloadf(&myG[j]) * SCL;
  __syncthreads();

  float part = 0.f;
  #pragma unroll 1
  for (int r = 0; r < ROWS_PER_WAVE; ++r) {
    const int i = rowbase + wv * ROWS_PER_WAVE + r;
    float4 pi = J1[i];
    float Fi = aloadf(&myF[i]) * SCL;
    float a4[4] = {0.f, 0.f, 0.f, 0.f};
    #pragma unroll
    for (int k = 0; k < CHUNKS; ++k) {
      float4 q = J2[k * 64 + lane];
      float dx = pi.x - q.x, dy = pi.y - q.y, dz = pi.z - q.z;
      float c = fmaf(dx, dx, fmaf(dy, dy, dz * dz));
      float U = fmaf(-SCL, c, Fi + q.w);
      a4[k & 3] = fmaf(exp2f(U), c, a4[k & 3]);
    }
    float lacc = wsum((a4[0] + a4[1]) + (a4[2] + a4[3]));
    if (lane == 0) part += sqrtf((float)NN * lacc + 1e-12f);
  }
  if (lane == 0) redbuf[wv] = part;
  __syncthreads();
  if (tid == 0) {
    float s = 0.f;
    #pragma unroll
    for (int w = 0; w < NWAVES; ++w) s += redbuf[w];
    atomicAdd(accum, s);
  }
  coopBarrier(gcnt, ggen, GRID);               // all partial sums at L3
  if (wg == 0 && tid == 0) out[0] = aloadf(accum) * (1.f / 16384.f);
}

extern "C" void kernel_launch(void* const* d_in, const int* in_sizes, int n_in,
                              void* d_out, int out_size, void* d_ws, size_t ws_size,
                              hipStream_t stream) {
  const float* pcs1 = (const float*)d_in[0];
  const float* pcs2 = (const float*)d_in[1];
  float* out = (float*)d_out;
  float* ws  = (float*)d_ws;
  // zero accum + barrier control block (after fArr/gArr = 2*8*2048 floats)
  hipMemsetAsync((char*)d_ws + (size_t)2 * BB * NN * 4, 0, 4096, stream);
  void* args[] = { &pcs1, &pcs2, &out, &ws };
  hipLaunchCooperativeKernel(reinterpret_cast<void*>(emd_sinkhorn),
                             dim3(GRID), dim3(WGS), args, 0, stream);
}

// Round 3
// 4546.406 us; speedup vs baseline: 2.3897x; 2.3897x over previous
//
#include <hip/hip_runtime.h>

#define BB 8
#define NN 2048
#define WGS 1024
#define GRID 256
#define WG_PER_B (GRID / BB)                 // 32 WGs per batch
#define ROWS_PER_WG (NN / WG_PER_B)          // 64
#define NWAVES (WGS / 64)                    // 16
#define ROWS_PER_WAVE (ROWS_PER_WG / NWAVES) // 4
#define CHUNKS (NN / 64)                     // 32
#define MAX_ITER 50

// eps = 0.005; work in log2 domain: SCL = log2(e)/eps
constexpr float SCL       = 288.5390081777927f;
constexpr float LN2f      = 0.6931471805599453f;
constexpr float EPSf      = 0.005f;
constexpr float EPS_LOGMU = -0.03812309493079699f; // 0.005 * (-ln 2048)

#define DEV_SCOPE __HIP_MEMORY_SCOPE_AGENT

__device__ __forceinline__ float aloadf(const float* p) {
  return __hip_atomic_load(p, __ATOMIC_RELAXED, DEV_SCOPE);
}
__device__ __forceinline__ void astoref(float* p, float v) {
  __hip_atomic_store(p, v, __ATOMIC_RELAXED, DEV_SCOPE);
}

__device__ __forceinline__ float wmax(float v) {
  #pragma unroll
  for (int d = 32; d; d >>= 1) v = fmaxf(v, __shfl_xor(v, d, 64));
  return v;
}
__device__ __forceinline__ float wsum(float v) {
  #pragma unroll
  for (int d = 32; d; d >>= 1) v += __shfl_xor(v, d, 64);
  return v;
}

// Sense-reversing barrier over nwg workgroups using relaxed agent atomics.
__device__ __forceinline__ void coopBarrier(int* cnt, int* gen, int nwg) {
  __syncthreads();   // compiler drains vmcnt(0) before s_barrier
  if (threadIdx.x == 0) {
    asm volatile("s_waitcnt vmcnt(0)" ::: "memory");
    int g = __hip_atomic_load(gen, __ATOMIC_RELAXED, DEV_SCOPE);
    int old = __hip_atomic_fetch_add(cnt, 1, __ATOMIC_RELAXED, DEV_SCOPE);
    if (old == nwg - 1) {
      __hip_atomic_store(cnt, 0, __ATOMIC_RELAXED, DEV_SCOPE);
      asm volatile("s_waitcnt vmcnt(0)" ::: "memory");
      __hip_atomic_store(gen, g + 1, __ATOMIC_RELAXED, DEV_SCOPE);
    } else {
      while (__hip_atomic_load(gen, __ATOMIC_RELAXED, DEV_SCOPE) == g)
        __builtin_amdgcn_s_sleep(4);
    }
  }
  __syncthreads();
}

// One wave computes ROWS_PER_WAVE=4 potential rows via two-pass logsumexp.
// No per-element cache: T is RECOMPUTED from LDS on pass 2 (avoids scratch
// spill — the round-1/2 killer). Each ds_read_b128 is amortized over 4 rows.
// JA[j] = {x,y,z,A_j}, A_j = (pot_j - |q_j|^2)*SCL (log2 units).
// T_ij = A_j + (2s p_i)·q_j ; row const B_i = -|p_i|^2 s folded at the end.
__device__ __forceinline__ void potentialRows(
    const float4* __restrict__ JA, const float4* __restrict__ JOwn,
    float* __restrict__ outPot, int rowbase, int wv, int lane)
{
  const int i0 = rowbase + wv * ROWS_PER_WAVE;
  float Xx[ROWS_PER_WAVE], Xy[ROWS_PER_WAVE], Xz[ROWS_PER_WAVE], Bc[ROWS_PER_WAVE];
  #pragma unroll
  for (int r = 0; r < ROWS_PER_WAVE; ++r) {
    float4 p = JOwn[i0 + r];                  // broadcast LDS read
    float pp = fmaf(p.x, p.x, fmaf(p.y, p.y, p.z * p.z));
    Xx[r] = 2.f * SCL * p.x; Xy[r] = 2.f * SCL * p.y; Xz[r] = 2.f * SCL * p.z;
    Bc[r] = -pp * SCL;
  }
  // pass 1: row maxima
  float m[ROWS_PER_WAVE];
  #pragma unroll
  for (int r = 0; r < ROWS_PER_WAVE; ++r) m[r] = -3.4e38f;
  #pragma unroll
  for (int k = 0; k < CHUNKS; ++k) {
    float4 q = JA[k * 64 + lane];
    #pragma unroll
    for (int r = 0; r < ROWS_PER_WAVE; ++r) {
      float T = fmaf(Xx[r], q.x, fmaf(Xy[r], q.y, fmaf(Xz[r], q.z, q.w)));
      m[r] = fmaxf(m[r], T);
    }
  }
  float M[ROWS_PER_WAVE];
  #pragma unroll
  for (int r = 0; r < ROWS_PER_WAVE; ++r) M[r] = wmax(m[r]);
  // pass 2: recompute T, accumulate exp2
  float s[ROWS_PER_WAVE];
  #pragma unroll
  for (int r = 0; r < ROWS_PER_WAVE; ++r) s[r] = 0.f;
  #pragma unroll
  for (int k = 0; k < CHUNKS; ++k) {
    float4 q = JA[k * 64 + lane];
    #pragma unroll
    for (int r = 0; r < ROWS_PER_WAVE; ++r) {
      float T = fmaf(Xx[r], q.x, fmaf(Xy[r], q.y, fmaf(Xz[r], q.z, q.w - M[r])));
      s[r] += exp2f(T);
    }
  }
  #pragma unroll
  for (int r = 0; r < ROWS_PER_WAVE; ++r) {
    float S = wsum(s[r]);
    if (lane == 0)
      astoref(&outPot[i0 + r], EPS_LOGMU - EPSf * LN2f * (Bc[r] + M[r] + log2f(S)));
  }
}

__global__ __launch_bounds__(WGS, 4) void emd_sinkhorn(
    const float* __restrict__ pcs1, const float* __restrict__ pcs2,
    float* __restrict__ out, float* __restrict__ ws)
{
  __shared__ float4 J1[NN];
  __shared__ float4 J2[NN];
  __shared__ float redbuf[NWAVES];

  const int wg = blockIdx.x, tid = threadIdx.x;
  const int b = wg / WG_PER_B, sub = wg % WG_PER_B;
  const int rowbase = sub * ROWS_PER_WG;
  const int lane = tid & 63, wv = tid >> 6;

  float* fArr = ws;
  float* gArr = ws + BB * NN;
  int*   ctrl = (int*)(ws + 2 * BB * NN);      // zeroed by host memset
  float* accum = (float*)&ctrl[0];             // own 64B line
  int* bcnt = &ctrl[16 + b * 32];              // per-batch counter line
  int* bgen = bcnt + 16;                       // per-batch gen line
  int* gcnt = &ctrl[16 + BB * 32];             // global barrier
  int* ggen = gcnt + 16;

  const float* p1 = pcs1 + (size_t)b * NN * 3;
  const float* p2 = pcs2 + (size_t)b * NN * 3;
  float* myF = fArr + b * NN;
  float* myG = gArr + b * NN;

  for (int i = tid; i < NN; i += WGS) {
    J1[i] = make_float4(p1[3 * i], p1[3 * i + 1], p1[3 * i + 2], 0.f);
    J2[i] = make_float4(p2[3 * i], p2[3 * i + 1], p2[3 * i + 2], 0.f);
  }
  __syncthreads();

  for (int it = 0; it < MAX_ITER; ++it) {
    // ---- f-update: stage A_j = (g_j - |q|^2)*SCL into J2.w
    for (int j = tid; j < NN; j += WGS) {
      float4 q = J2[j];
      float qq = fmaf(q.x, q.x, fmaf(q.y, q.y, q.z * q.z));
      float gj = (it == 0) ? 0.f : aloadf(&myG[j]);
      J2[j].w = (gj - qq) * SCL;
    }
    __syncthreads();
    potentialRows(J2, J1, myF, rowbase, wv, lane);
    coopBarrier(bcnt, bgen, WG_PER_B);         // f complete, batch-wide

    // ---- g-update: stage A_i = (f_i - |p|^2)*SCL into J1.w
    for (int i = tid; i < NN; i += WGS) {
      float4 p = J1[i];
      float pp = fmaf(p.x, p.x, fmaf(p.y, p.y, p.z * p.z));
      J1[i].w = (aloadf(&myF[i]) - pp) * SCL;
    }
    __syncthreads();
    potentialRows(J1, J2, myG, rowbase, wv, lane);
    coopBarrier(bcnt, bgen, WG_PER_B);         // g complete
  }

  // ---- final: dist_i = N * sum_j exp2((f_i+g_j-C_ij)*SCL) * C_ij
  for (int j = tid; j < NN; j += WGS) J2[j].w = aloadf(&myG[j]) * SCL;
  __syncthreads();

  float part = 0.f;
  #pragma unroll 1
  for (int r = 0; r < ROWS_PER_WAVE; ++r) {
    const int i = rowbase + wv * ROWS_PER_WAVE + r;
    float4 pi = J1[i];
    float Fi = aloadf(&myF[i]) * SCL;
    float a4[4] = {0.f, 0.f, 0.f, 0.f};
    #pragma unroll
    for (int k = 0; k < CHUNKS; ++k) {
      float4 q = J2[k * 64 + lane];
      float dx = pi.x - q.x, dy = pi.y - q.y, dz = pi.z - q.z;
      float c = fmaf(dx, dx, fmaf(dy, dy, dz * dz));
      float U = fmaf(-SCL, c, Fi + q.w);
      a4[k & 3] = fmaf(exp2f(U), c, a4[k & 3]);
    }
    float lacc = wsum((a4[0] + a4[1]) + (a4[2] + a4[3]));
    if (lane == 0) part += sqrtf((float)NN * lacc + 1e-12f);
  }
  if (lane == 0) redbuf[wv] = part;
  __syncthreads();
  if (tid == 0) {
    float s = 0.f;
    #pragma unroll
    for (int w = 0; w < NWAVES; ++w) s += redbuf[w];
    atomicAdd(accum, s);
  }
  coopBarrier(gcnt, ggen, GRID);               // all partial sums at L3
  if (wg == 0 && tid == 0) out[0] = aloadf(accum) * (1.f / 16384.f);
}

extern "C" void kernel_launch(void* const* d_in, const int* in_sizes, int n_in,
                              void* d_out, int out_size, void* d_ws, size_t ws_size,
                              hipStream_t stream) {
  const float* pcs1 = (const float*)d_in[0];
  const float* pcs2 = (const float*)d_in[1];
  float* out = (float*)d_out;
  float* ws  = (float*)d_ws;
  // zero accum + barrier control block (after fArr/gArr = 2*8*2048 floats)
  hipMemsetAsync((char*)d_ws + (size_t)2 * BB * NN * 4, 0, 4096, stream);
  void* args[] = { &pcs1, &pcs2, &out, &ws };
  hipLaunchCooperativeKernel(reinterpret_cast<void*>(emd_sinkhorn),
                             dim3(GRID), dim3(WGS), args, 0, stream);
}

// Round 4
// 4010.699 us; speedup vs baseline: 2.7088x; 1.1336x over previous
//
#include <hip/hip_runtime.h>

#define BB 8
#define NN 2048
#define WGS 1024
#define GRID 256
#define WG_PER_B (GRID / BB)                 // 32 WGs per batch
#define ROWS_PER_WG (NN / WG_PER_B)          // 64
#define NWAVES (WGS / 64)                    // 16
#define ROWS_PER_WAVE (ROWS_PER_WG / NWAVES) // 4
#define CHUNKS (NN / 64)                     // 32
#define MAX_ITER 50

// eps = 0.005; work in log2 domain: SCL = log2(e)/eps
constexpr float SCL       = 288.5390081777927f;
constexpr float LN2f      = 0.6931471805599453f;
constexpr float EPSf      = 0.005f;
constexpr float EPS_LOGMU = -0.03812309493079699f; // 0.005 * (-ln 2048)

#define DEV_SCOPE __HIP_MEMORY_SCOPE_AGENT

__device__ __forceinline__ float aloadf(const float* p) {
  return __hip_atomic_load(p, __ATOMIC_RELAXED, DEV_SCOPE);
}
__device__ __forceinline__ void astoref(float* p, float v) {
  __hip_atomic_store(p, v, __ATOMIC_RELAXED, DEV_SCOPE);
}

// raw v_exp_f32 / v_log_f32 (log2 domain; flush-to-zero is desired here)
__device__ __forceinline__ float fexp2(float x) { return __builtin_amdgcn_exp2f(x); }
__device__ __forceinline__ float flog2(float x) { return __builtin_amdgcn_logf(x); }

__device__ __forceinline__ float wmax(float v) {
  #pragma unroll
  for (int d = 32; d; d >>= 1) v = fmaxf(v, __shfl_xor(v, d, 64));
  return v;
}
__device__ __forceinline__ float wsum(float v) {
  #pragma unroll
  for (int d = 32; d; d >>= 1) v += __shfl_xor(v, d, 64);
  return v;
}

// Sense-reversing barrier over nwg workgroups using relaxed agent atomics.
// Poll with escalating s_sleep backoff to keep fabric traffic negligible.
__device__ __forceinline__ void coopBarrier(int* cnt, int* gen, int nwg) {
  __syncthreads();   // drains vmcnt(0) before s_barrier
  if (threadIdx.x == 0) {
    asm volatile("s_waitcnt vmcnt(0)" ::: "memory");
    int g = __hip_atomic_load(gen, __ATOMIC_RELAXED, DEV_SCOPE);
    int old = __hip_atomic_fetch_add(cnt, 1, __ATOMIC_RELAXED, DEV_SCOPE);
    if (old == nwg - 1) {
      __hip_atomic_store(cnt, 0, __ATOMIC_RELAXED, DEV_SCOPE);
      asm volatile("s_waitcnt vmcnt(0)" ::: "memory");
      __hip_atomic_store(gen, g + 1, __ATOMIC_RELAXED, DEV_SCOPE);
    } else {
      int spins = 0;
      while (__hip_atomic_load(gen, __ATOMIC_RELAXED, DEV_SCOPE) == g) {
        if (spins < 2) __builtin_amdgcn_s_sleep(8);
        else           __builtin_amdgcn_s_sleep(64);
        ++spins;
      }
    }
  }
  __syncthreads();
}

// One wave computes ROWS_PER_WAVE=4 potential rows via two-pass logsumexp.
// T is RECOMPUTED from LDS on pass 2 (no per-element cache -> no scratch).
// JA[j] = {x,y,z,A_j}, A_j = (pot_j - |q_j|^2)*SCL (log2 units).
// T_ij = A_j + (2s p_i)·q_j ; row const B_i = -|p_i|^2 s folded at the end.
__device__ __forceinline__ void potentialRows(
    const float4* __restrict__ JA, const float4* __restrict__ JOwn,
    float* __restrict__ outPot, int rowbase, int wv, int lane)
{
  const int i0 = rowbase + wv * ROWS_PER_WAVE;
  float Xx[ROWS_PER_WAVE], Xy[ROWS_PER_WAVE], Xz[ROWS_PER_WAVE], Bc[ROWS_PER_WAVE];
  #pragma unroll
  for (int r = 0; r < ROWS_PER_WAVE; ++r) {
    float4 p = JOwn[i0 + r];                  // broadcast LDS read
    float pp = fmaf(p.x, p.x, fmaf(p.y, p.y, p.z * p.z));
    Xx[r] = 2.f * SCL * p.x; Xy[r] = 2.f * SCL * p.y; Xz[r] = 2.f * SCL * p.z;
    Bc[r] = -pp * SCL;
  }
  // pass 1: row maxima
  float m[ROWS_PER_WAVE];
  #pragma unroll
  for (int r = 0; r < ROWS_PER_WAVE; ++r) m[r] = -3.4e38f;
  #pragma unroll
  for (int k = 0; k < CHUNKS; ++k) {
    float4 q = JA[k * 64 + lane];
    #pragma unroll
    for (int r = 0; r < ROWS_PER_WAVE; ++r) {
      float T = fmaf(Xx[r], q.x, fmaf(Xy[r], q.y, fmaf(Xz[r], q.z, q.w)));
      m[r] = fmaxf(m[r], T);
    }
  }
  float M[ROWS_PER_WAVE];
  #pragma unroll
  for (int r = 0; r < ROWS_PER_WAVE; ++r) M[r] = wmax(m[r]);
  // pass 2: recompute T, accumulate exp2
  float s[ROWS_PER_WAVE];
  #pragma unroll
  for (int r = 0; r < ROWS_PER_WAVE; ++r) s[r] = 0.f;
  #pragma unroll
  for (int k = 0; k < CHUNKS; ++k) {
    float4 q = JA[k * 64 + lane];
    #pragma unroll
    for (int r = 0; r < ROWS_PER_WAVE; ++r) {
      float T = fmaf(Xx[r], q.x, fmaf(Xy[r], q.y, fmaf(Xz[r], q.z, q.w - M[r])));
      s[r] += fexp2(T);
    }
  }
  #pragma unroll
  for (int r = 0; r < ROWS_PER_WAVE; ++r) {
    float S = wsum(s[r]);
    if (lane == 0)
      astoref(&outPot[i0 + r], EPS_LOGMU - EPSf * LN2f * (Bc[r] + M[r] + flog2(S)));
  }
}

__global__ __launch_bounds__(WGS) void emd_sinkhorn(
    const float* __restrict__ pcs1, const float* __restrict__ pcs2,
    float* __restrict__ out, float* __restrict__ ws)
{
  __shared__ float4 J1[NN];
  __shared__ float4 J2[NN];
  __shared__ float redbuf[NWAVES];

  const int wg = blockIdx.x, tid = threadIdx.x;
  const int b = wg / WG_PER_B, sub = wg % WG_PER_B;
  const int rowbase = sub * ROWS_PER_WG;
  const int lane = tid & 63, wv = tid >> 6;

  float* fArr = ws;
  float* gArr = ws + BB * NN;
  int*   ctrl = (int*)(ws + 2 * BB * NN);      // zeroed by host memset
  float* accum = (float*)&ctrl[0];             // own 64B line
  int* bcnt = &ctrl[16 + b * 32];              // per-batch counter line
  int* bgen = bcnt + 16;                       // per-batch gen line
  int* gcnt = &ctrl[16 + BB * 32];             // global barrier
  int* ggen = gcnt + 16;

  const float* p1 = pcs1 + (size_t)b * NN * 3;
  const float* p2 = pcs2 + (size_t)b * NN * 3;
  float* myF = fArr + b * NN;
  float* myG = gArr + b * NN;

  for (int i = tid; i < NN; i += WGS) {
    J1[i] = make_float4(p1[3 * i], p1[3 * i + 1], p1[3 * i + 2], 0.f);
    J2[i] = make_float4(p2[3 * i], p2[3 * i + 1], p2[3 * i + 2], 0.f);
  }
  __syncthreads();

  for (int it = 0; it < MAX_ITER; ++it) {
    // ---- f-update: stage A_j = (g_j - |q|^2)*SCL into J2.w
    for (int j = tid; j < NN; j += WGS) {
      float4 q = J2[j];
      float qq = fmaf(q.x, q.x, fmaf(q.y, q.y, q.z * q.z));
      float gj = (it == 0) ? 0.f : aloadf(&myG[j]);
      J2[j].w = (gj - qq) * SCL;
    }
    __syncthreads();
    potentialRows(J2, J1, myF, rowbase, wv, lane);
    coopBarrier(bcnt, bgen, WG_PER_B);         // f complete, batch-wide

    // ---- g-update: stage A_i = (f_i - |p|^2)*SCL into J1.w
    for (int i = tid; i < NN; i += WGS) {
      float4 p = J1[i];
      float pp = fmaf(p.x, p.x, fmaf(p.y, p.y, p.z * p.z));
      J1[i].w = (aloadf(&myF[i]) - pp) * SCL;
    }
    __syncthreads();
    potentialRows(J1, J2, myG, rowbase, wv, lane);
    coopBarrier(bcnt, bgen, WG_PER_B);         // g complete
  }

  // ---- final: dist_i = N * sum_j exp2((f_i+g_j-C_ij)*SCL) * C_ij
  for (int j = tid; j < NN; j += WGS) J2[j].w = aloadf(&myG[j]) * SCL;
  __syncthreads();

  float part = 0.f;
  #pragma unroll 1
  for (int r = 0; r < ROWS_PER_WAVE; ++r) {
    const int i = rowbase + wv * ROWS_PER_WAVE + r;
    float4 pi = J1[i];
    float Fi = aloadf(&myF[i]) * SCL;
    float a4[4] = {0.f, 0.f, 0.f, 0.f};
    #pragma unroll
    for (int k = 0; k < CHUNKS; ++k) {
      float4 q = J2[k * 64 + lane];
      float dx = pi.x - q.x, dy = pi.y - q.y, dz = pi.z - q.z;
      float c = fmaf(dx, dx, fmaf(dy, dy, dz * dz));
      float U = fmaf(-SCL, c, Fi + q.w);
      a4[k & 3] = fmaf(fexp2(U), c, a4[k & 3]);
    }
    float lacc = wsum((a4[0] + a4[1]) + (a4[2] + a4[3]));
    if (lane == 0) part += sqrtf((float)NN * lacc + 1e-12f);
  }
  if (lane == 0) redbuf[wv] = part;
  __syncthreads();
  if (tid == 0) {
    float s = 0.f;
    #pragma unroll
    for (int w = 0; w < NWAVES; ++w) s += redbuf[w];
    atomicAdd(accum, s);
  }
  coopBarrier(gcnt, ggen, GRID);               // all partial sums at L3
  if (wg == 0 && tid == 0) out[0] = aloadf(accum) * (1.f / 16384.f);
}

extern "C" void kernel_launch(void* const* d_in, const int* in_sizes, int n_in,
                              void* d_out, int out_size, void* d_ws, size_t ws_size,
                              hipStream_t stream) {
  const float* pcs1 = (const float*)d_in[0];
  const float* pcs2 = (const float*)d_in[1];
  float* out = (float*)d_out;
  float* ws  = (float*)d_ws;
  // zero accum + barrier control block (after fArr/gArr = 2*8*2048 floats)
  hipMemsetAsync((char*)d_ws + (size_t)2 * BB * NN * 4, 0, 4096, stream);
  void* args[] = { &pcs1, &pcs2, &out, &ws };
  hipLaunchCooperativeKernel(reinterpret_cast<void*>(emd_sinkhorn),
                             dim3(GRID), dim3(WGS), args, 0, stream);
}

// Round 5
// 3528.138 us; speedup vs baseline: 3.0793x; 1.1368x over previous
//
#include <hip/hip_runtime.h>

#define BB 8
#define NN 2048
#define WGS 1024
#define GRID 256
#define WG_PER_B (GRID / BB)                 // 32 WGs per batch
#define ROWS_PER_WG (NN / WG_PER_B)          // 64
#define NWAVES (WGS / 64)                    // 16
#define ROWS_PER_WAVE (ROWS_PER_WG / NWAVES) // 4
#define CHUNKS (NN / 64)                     // 32
#define MAX_ITER 50
// pad LDS past 81920 B so the occupancy heuristic targets 1 WG/CU ->
// VGPR budget 128, not 64 (we only ever run 1 WG/CU: grid == #CUs).
#define REDPAD 5632

// eps = 0.005; work in log2 domain: SCL = log2(e)/eps
constexpr float SCL       = 288.5390081777927f;
constexpr float LN2f      = 0.6931471805599453f;
constexpr float EPSf      = 0.005f;
constexpr float EPS_LOGMU = -0.03812309493079699f; // 0.005 * (-ln 2048)

#define DEV_SCOPE __HIP_MEMORY_SCOPE_AGENT

__device__ __forceinline__ float aloadf(const float* p) {
  return __hip_atomic_load(p, __ATOMIC_RELAXED, DEV_SCOPE);
}
__device__ __forceinline__ void astoref(float* p, float v) {
  __hip_atomic_store(p, v, __ATOMIC_RELAXED, DEV_SCOPE);
}

// raw v_exp_f32 / v_log_f32 (log2 domain; flush-to-zero is desired here)
__device__ __forceinline__ float fexp2(float x) { return __builtin_amdgcn_exp2f(x); }
__device__ __forceinline__ float flog2(float x) { return __builtin_amdgcn_logf(x); }

__device__ __forceinline__ float wmax(float v) {
  #pragma unroll
  for (int d = 32; d; d >>= 1) v = fmaxf(v, __shfl_xor(v, d, 64));
  return v;
}
__device__ __forceinline__ float wsum(float v) {
  #pragma unroll
  for (int d = 32; d; d >>= 1) v += __shfl_xor(v, d, 64);
  return v;
}

// Sense-reversing barrier over nwg workgroups using relaxed agent atomics.
__device__ __forceinline__ void coopBarrier(int* cnt, int* gen, int nwg) {
  __syncthreads();
  if (threadIdx.x == 0) {
    asm volatile("s_waitcnt vmcnt(0)" ::: "memory");
    int g = __hip_atomic_load(gen, __ATOMIC_RELAXED, DEV_SCOPE);
    int old = __hip_atomic_fetch_add(cnt, 1, __ATOMIC_RELAXED, DEV_SCOPE);
    if (old == nwg - 1) {
      __hip_atomic_store(cnt, 0, __ATOMIC_RELAXED, DEV_SCOPE);
      asm volatile("s_waitcnt vmcnt(0)" ::: "memory");
      __hip_atomic_store(gen, g + 1, __ATOMIC_RELAXED, DEV_SCOPE);
    } else {
      int spins = 0;
      while (__hip_atomic_load(gen, __ATOMIC_RELAXED, DEV_SCOPE) == g) {
        if (spins < 2) __builtin_amdgcn_s_sleep(8);
        else           __builtin_amdgcn_s_sleep(64);
        ++spins;
      }
    }
  }
  __syncthreads();
}

// One wave computes ROWS_PER_WAVE=4 potential rows via two-pass logsumexp.
// T is RECOMPUTED from LDS on pass 2 (no per-element cache -> no scratch).
__device__ __forceinline__ void potentialRows(
    const float4* __restrict__ JA, const float4* __restrict__ JOwn,
    float* __restrict__ outPot, int rowbase, int wv, int lane)
{
  const int i0 = rowbase + wv * ROWS_PER_WAVE;
  float Xx[ROWS_PER_WAVE], Xy[ROWS_PER_WAVE], Xz[ROWS_PER_WAVE], Bc[ROWS_PER_WAVE];
  #pragma unroll
  for (int r = 0; r < ROWS_PER_WAVE; ++r) {
    float4 p = JOwn[i0 + r];                  // broadcast LDS read
    float pp = fmaf(p.x, p.x, fmaf(p.y, p.y, p.z * p.z));
    Xx[r] = 2.f * SCL * p.x; Xy[r] = 2.f * SCL * p.y; Xz[r] = 2.f * SCL * p.z;
    Bc[r] = -pp * SCL;
  }
  float m[ROWS_PER_WAVE];
  #pragma unroll
  for (int r = 0; r < ROWS_PER_WAVE; ++r) m[r] = -3.4e38f;
  #pragma unroll
  for (int k = 0; k < CHUNKS; ++k) {
    float4 q = JA[k * 64 + lane];
    #pragma unroll
    for (int r = 0; r < ROWS_PER_WAVE; ++r) {
      float T = fmaf(Xx[r], q.x, fmaf(Xy[r], q.y, fmaf(Xz[r], q.z, q.w)));
      m[r] = fmaxf(m[r], T);
    }
  }
  float M[ROWS_PER_WAVE];
  #pragma unroll
  for (int r = 0; r < ROWS_PER_WAVE; ++r) M[r] = wmax(m[r]);
  float s[ROWS_PER_WAVE];
  #pragma unroll
  for (int r = 0; r < ROWS_PER_WAVE; ++r) s[r] = 0.f;
  #pragma unroll
  for (int k = 0; k < CHUNKS; ++k) {
    float4 q = JA[k * 64 + lane];
    #pragma unroll
    for (int r = 0; r < ROWS_PER_WAVE; ++r) {
      float T = fmaf(Xx[r], q.x, fmaf(Xy[r], q.y, fmaf(Xz[r], q.z, q.w - M[r])));
      s[r] += fexp2(T);
    }
  }
  #pragma unroll
  for (int r = 0; r < ROWS_PER_WAVE; ++r) {
    float S = wsum(s[r]);
    if (lane == 0)
      astoref(&outPot[i0 + r], EPS_LOGMU - EPSf * LN2f * (Bc[r] + M[r] + flog2(S)));
  }
}

__global__ __launch_bounds__(WGS)
__attribute__((amdgpu_waves_per_eu(4, 4)))
void emd_sinkhorn(
    const float* __restrict__ pcs1, const float* __restrict__ pcs2,
    float* __restrict__ out, float* __restrict__ ws)
{
  __shared__ float4 J1[NN];
  __shared__ float4 J2[NN];
  __shared__ float redbuf[NWAVES + REDPAD];   // oversized: LDS occupancy pad

  const int wg = blockIdx.x, tid = threadIdx.x;
  const int b = wg / WG_PER_B, sub = wg % WG_PER_B;
  const int rowbase = sub * ROWS_PER_WG;
  const int lane = tid & 63, wv = tid >> 6;

  float* fArr = ws;
  float* gArr = ws + BB * NN;
  int*   ctrl = (int*)(ws + 2 * BB * NN);      // zeroed by host memset
  float* accum = (float*)&ctrl[0];             // own 64B line
  int* bcnt = &ctrl[16 + b * 32];              // per-batch counter line
  int* bgen = bcnt + 16;                       // per-batch gen line
  int* gcnt = &ctrl[16 + BB * 32];             // global barrier
  int* ggen = gcnt + 16;

  const float* p1 = pcs1 + (size_t)b * NN * 3;
  const float* p2 = pcs2 + (size_t)b * NN * 3;
  float* myF = fArr + b * NN;
  float* myG = gArr + b * NN;

  for (int i = tid; i < NN; i += WGS) {
    J1[i] = make_float4(p1[3 * i], p1[3 * i + 1], p1[3 * i + 2], 0.f);
    J2[i] = make_float4(p2[3 * i], p2[3 * i + 1], p2[3 * i + 2], 0.f);
  }
  __syncthreads();

  for (int it = 0; it < MAX_ITER; ++it) {
    // ---- f-update: stage A_j = (g_j - |q|^2)*SCL into J2.w
    for (int j = tid; j < NN; j += WGS) {
      float4 q = J2[j];
      float qq = fmaf(q.x, q.x, fmaf(q.y, q.y, q.z * q.z));
      float gj = (it == 0) ? 0.f : aloadf(&myG[j]);
      J2[j].w = (gj - qq) * SCL;
    }
    __syncthreads();
    potentialRows(J2, J1, myF, rowbase, wv, lane);
    coopBarrier(bcnt, bgen, WG_PER_B);         // f complete, batch-wide

    // ---- g-update: stage A_i = (f_i - |p|^2)*SCL into J1.w
    for (int i = tid; i < NN; i += WGS) {
      float4 p = J1[i];
      float pp = fmaf(p.x, p.x, fmaf(p.y, p.y, p.z * p.z));
      J1[i].w = (aloadf(&myF[i]) - pp) * SCL;
    }
    __syncthreads();
    potentialRows(J1, J2, myG, rowbase, wv, lane);
    coopBarrier(bcnt, bgen, WG_PER_B);         // g complete
  }

  // ---- final: dist_i = N * sum_j exp2((f_i+g_j-C_ij)*SCL) * C_ij
  for (int j = tid; j < NN; j += WGS) J2[j].w = aloadf(&myG[j]) * SCL;
  __syncthreads();

  float part = 0.f;
  #pragma unroll 1
  for (int r = 0; r < ROWS_PER_WAVE; ++r) {
    const int i = rowbase + wv * ROWS_PER_WAVE + r;
    float4 pi = J1[i];
    float Fi = aloadf(&myF[i]) * SCL;
    float a4[4] = {0.f, 0.f, 0.f, 0.f};
    #pragma unroll
    for (int k = 0; k < CHUNKS; ++k) {
      float4 q = J2[k * 64 + lane];
      float dx = pi.x - q.x, dy = pi.y - q.y, dz = pi.z - q.z;
      float c = fmaf(dx, dx, fmaf(dy, dy, dz * dz));
      float U = fmaf(-SCL, c, Fi + q.w);
      a4[k & 3] = fmaf(fexp2(U), c, a4[k & 3]);
    }
    float lacc = wsum((a4[0] + a4[1]) + (a4[2] + a4[3]));
    if (lane == 0) part += sqrtf((float)NN * lacc + 1e-12f);
  }
  if (lane == 0) redbuf[wv] = part;
  __syncthreads();
  if (tid == 0) {
    float s = 0.f;
    #pragma unroll
    for (int w = 0; w < NWAVES; ++w) s += redbuf[w];
    atomicAdd(accum, s);
  }
  coopBarrier(gcnt, ggen, GRID);               // all partial sums at L3
  if (wg == 0 && tid == 0) out[0] = aloadf(accum) * (1.f / 16384.f);
}

extern "C" void kernel_launch(void* const* d_in, const int* in_sizes, int n_in,
                              void* d_out, int out_size, void* d_ws, size_t ws_size,
                              hipStream_t stream) {
  const float* pcs1 = (const float*)d_in[0];
  const float* pcs2 = (const float*)d_in[1];
  float* out = (float*)d_out;
  float* ws  = (float*)d_ws;
  // zero accum + barrier control block (after fArr/gArr = 2*8*2048 floats)
  hipMemsetAsync((char*)d_ws + (size_t)2 * BB * NN * 4, 0, 4096, stream);
  void* args[] = { &pcs1, &pcs2, &out, &ws };
  hipLaunchCooperativeKernel(reinterpret_cast<void*>(emd_sinkhorn),
                             dim3(GRID), dim3(WGS), args, 0, stream);
}

// Round 8
// 1115.724 us; speedup vs baseline: 9.7375x; 3.1622x over previous
//
#include <hip/hip_runtime.h>

#define BB 8
#define NN 2048
#define WGS 1024
#define GRID 256
#define WG_PER_B (GRID / BB)                 // 32 WGs per batch
#define ROWS_PER_WG (NN / WG_PER_B)          // 64
#define NWAVES (WGS / 64)                    // 16
#define ROWS_PER_WAVE (ROWS_PER_WG / NWAVES) // 4
#define CHUNKS (NN / 64)                     // 32
#define MAX_ITER 50

// eps = 0.005; work in log2 domain: SCL = log2(e)/eps
constexpr float SCL       = 288.5390081777927f;
constexpr float LN2f      = 0.6931471805599453f;
constexpr float EPSf      = 0.005f;
constexpr float EPS_LOGMU = -0.03812309493079699f; // 0.005 * (-ln 2048)

__device__ __forceinline__ float fexp2(float x) { return __builtin_amdgcn_exp2f(x); }
__device__ __forceinline__ float flog2(float x) { return __builtin_amdgcn_logf(x); }

__device__ __forceinline__ float wmax(float v) {
  #pragma unroll
  for (int d = 32; d; d >>= 1) v = fmaxf(v, __shfl_xor(v, d, 64));
  return v;
}
__device__ __forceinline__ float wsum(float v) {
  #pragma unroll
  for (int d = 32; d; d >>= 1) v += __shfl_xor(v, d, 64);
  return v;
}

// One half-iteration of Sinkhorn: potOut_i = eps*log_mu - eps*lse_j((potIn_j - C_ij)/eps)
// over the 2048 points of `cols`, for the 64 rows of `rows` owned by this WG.
// Cross-launch visibility comes from kernel boundaries on the stream — no
// inter-WG sync of any kind (rounds 6/7: cooperative spin-barrier hang).
__global__ __launch_bounds__(WGS)
__attribute__((amdgpu_waves_per_eu(4, 4)))
void half_iter(const float* __restrict__ rows, const float* __restrict__ cols,
               const float* __restrict__ potIn, float* __restrict__ potOut)
{
  __shared__ float4 J[NN];   // {x,y,z, (pot_j - |q_j|^2)*SCL}
  const int wg = blockIdx.x, tid = threadIdx.x;
  const int b = wg >> 5, sub = wg & 31;
  const int lane = tid & 63, wv = tid >> 6;

  const float* C  = cols  + (size_t)b * NN * 3;
  const float* PI = potIn + b * NN;
  for (int j = tid; j < NN; j += WGS) {
    float x = C[3*j], y = C[3*j+1], z = C[3*j+2];
    float qq = fmaf(x, x, fmaf(y, y, z * z));
    J[j] = make_float4(x, y, z, (PI[j] - qq) * SCL);
  }
  __syncthreads();

  const int i0 = sub * ROWS_PER_WG + wv * ROWS_PER_WAVE;
  const float* R = rows + (size_t)b * NN * 3 + (size_t)i0 * 3;
  const float p0x=R[0], p0y=R[1],  p0z=R[2];
  const float p1x=R[3], p1y=R[4],  p1z=R[5];
  const float p2x=R[6], p2y=R[7],  p2z=R[8];
  const float p3x=R[9], p3y=R[10], p3z=R[11];
  const float X0x=2.f*SCL*p0x, X0y=2.f*SCL*p0y, X0z=2.f*SCL*p0z;
  const float X1x=2.f*SCL*p1x, X1y=2.f*SCL*p1y, X1z=2.f*SCL*p1z;
  const float X2x=2.f*SCL*p2x, X2y=2.f*SCL*p2y, X2z=2.f*SCL*p2z;
  const float X3x=2.f*SCL*p3x, X3y=2.f*SCL*p3y, X3z=2.f*SCL*p3z;
  const float B0 = -SCL * fmaf(p0x, p0x, fmaf(p0y, p0y, p0z * p0z));
  const float B1 = -SCL * fmaf(p1x, p1x, fmaf(p1y, p1y, p1z * p1z));
  const float B2 = -SCL * fmaf(p2x, p2x, fmaf(p2y, p2y, p2z * p2z));
  const float B3 = -SCL * fmaf(p3x, p3x, fmaf(p3y, p3y, p3z * p3z));

  // pass 1: row maxima (unroll capped: full unroll clustered 32 b128 loads
  // -> 128 live VGPRs -> scratch spill = rounds-1..5 constant WRITE_SIZE)
  float m0 = -3.4e38f, m1 = -3.4e38f, m2 = -3.4e38f, m3 = -3.4e38f;
  #pragma unroll 4
  for (int k = 0; k < CHUNKS; ++k) {
    float4 q = J[k * 64 + lane];
    m0 = fmaxf(m0, fmaf(X0x, q.x, fmaf(X0y, q.y, fmaf(X0z, q.z, q.w))));
    m1 = fmaxf(m1, fmaf(X1x, q.x, fmaf(X1y, q.y, fmaf(X1z, q.z, q.w))));
    m2 = fmaxf(m2, fmaf(X2x, q.x, fmaf(X2y, q.y, fmaf(X2z, q.z, q.w))));
    m3 = fmaxf(m3, fmaf(X3x, q.x, fmaf(X3y, q.y, fmaf(X3z, q.z, q.w))));
  }
  const float M0 = wmax(m0), M1 = wmax(m1), M2 = wmax(m2), M3 = wmax(m3);

  // pass 2: recompute T, accumulate exp2
  float s0 = 0.f, s1 = 0.f, s2 = 0.f, s3 = 0.f;
  #pragma unroll 4
  for (int k = 0; k < CHUNKS; ++k) {
    float4 q = J[k * 64 + lane];
    s0 += fexp2(fmaf(X0x, q.x, fmaf(X0y, q.y, fmaf(X0z, q.z, q.w - M0))));
    s1 += fexp2(fmaf(X1x, q.x, fmaf(X1y, q.y, fmaf(X1z, q.z, q.w - M1))));
    s2 += fexp2(fmaf(X2x, q.x, fmaf(X2y, q.y, fmaf(X2z, q.z, q.w - M2))));
    s3 += fexp2(fmaf(X3x, q.x, fmaf(X3y, q.y, fmaf(X3z, q.z, q.w - M3))));
  }
  const float S0 = wsum(s0), S1 = wsum(s1), S2 = wsum(s2), S3 = wsum(s3);
  if (lane == 0) {
    float* PO = potOut + b * NN + i0;
    PO[0] = EPS_LOGMU - EPSf*LN2f*(B0 + M0 + flog2(S0));
    PO[1] = EPS_LOGMU - EPSf*LN2f*(B1 + M1 + flog2(S1));
    PO[2] = EPS_LOGMU - EPSf*LN2f*(B2 + M2 + flog2(S2));
    PO[3] = EPS_LOGMU - EPSf*LN2f*(B3 + M3 + flog2(S3));
  }
}

// dist_i = N * sum_j exp2((f_i + g_j - C_ij)*SCL) * C_ij ; per-WG partial
// sum of sqrt(dist) -> partials[wg] (plain store, no atomics).
__global__ __launch_bounds__(WGS)
__attribute__((amdgpu_waves_per_eu(4, 4)))
void emd_finalize(const float* __restrict__ pcs1, const float* __restrict__ pcs2,
                  const float* __restrict__ fArr, const float* __restrict__ gArr,
                  float* __restrict__ partials)
{
  __shared__ float4 J[NN];   // {x,y,z, g_j*SCL}
  __shared__ float red[NWAVES];
  const int wg = blockIdx.x, tid = threadIdx.x;
  const int b = wg >> 5, sub = wg & 31;
  const int lane = tid & 63, wv = tid >> 6;

  const float* C = pcs2 + (size_t)b * NN * 3;
  const float* G = gArr + b * NN;
  for (int j = tid; j < NN; j += WGS) {
    J[j] = make_float4(C[3*j], C[3*j+1], C[3*j+2], G[j] * SCL);
  }
  __syncthreads();

  const int i0 = sub * ROWS_PER_WG + wv * ROWS_PER_WAVE;
  const float* R = pcs1 + (size_t)b * NN * 3;
  const float* F = fArr + b * NN;
  float part = 0.f;
  #pragma unroll 1
  for (int r = 0; r < ROWS_PER_WAVE; ++r) {
    const int i = i0 + r;
    const float px = R[3*i], py = R[3*i+1], pz = R[3*i+2];
    const float Fi = F[i] * SCL;
    float a0 = 0.f, a1 = 0.f;
    #pragma unroll 2
    for (int k = 0; k < CHUNKS; k += 2) {
      float4 qa = J[k * 64 + lane];
      float4 qb = J[(k + 1) * 64 + lane];
      float dxa = px - qa.x, dya = py - qa.y, dza = pz - qa.z;
      float ca = fmaf(dxa, dxa, fmaf(dya, dya, dza * dza));
      a0 = fmaf(fexp2(fmaf(-SCL, ca, Fi + qa.w)), ca, a0);
      float dxb = px - qb.x, dyb = py - qb.y, dzb = pz - qb.z;
      float cb = fmaf(dxb, dxb, fmaf(dyb, dyb, dzb * dzb));
      a1 = fmaf(fexp2(fmaf(-SCL, cb, Fi + qb.w)), cb, a1);
    }
    float lacc = wsum(a0 + a1);
    if (lane == 0) part += sqrtf((float)NN * lacc + 1e-12f);
  }
  if (lane == 0) red[wv] = part;
  __syncthreads();
  if (tid == 0) {
    float s = 0.f;
    #pragma unroll
    for (int w = 0; w < NWAVES; ++w) s += red[w];
    partials[wg] = s;
  }
}

// Deterministic 256-way reduction -> mean.
__global__ void emd_reduce(const float* __restrict__ partials, float* __restrict__ out)
{
  __shared__ float sb[4];
  const int tid = threadIdx.x;
  float v = wsum(partials[tid]);
  if ((tid & 63) == 0) sb[tid >> 6] = v;
  __syncthreads();
  if (tid == 0) out[0] = (sb[0] + sb[1] + sb[2] + sb[3]) * (1.f / 16384.f);
}

extern "C" void kernel_launch(void* const* d_in, const int* in_sizes, int n_in,
                              void* d_out, int out_size, void* d_ws, size_t ws_size,
                              hipStream_t stream) {
  const float* pcs1 = (const float*)d_in[0];
  const float* pcs2 = (const float*)d_in[1];
  float* out      = (float*)d_out;
  float* fArr     = (float*)d_ws;                  // BB*NN floats
  float* gArr     = fArr + BB * NN;                // BB*NN floats
  float* partials = gArr + BB * NN;                // GRID floats

  // g starts at 0 (reference: g0 = zeros); first f-update reads it.
  hipMemsetAsync(gArr, 0, (size_t)BB * NN * sizeof(float), stream);

  for (int it = 0; it < MAX_ITER; ++it) {
    half_iter<<<GRID, WGS, 0, stream>>>(pcs1, pcs2, gArr, fArr); // f-update
    half_iter<<<GRID, WGS, 0, stream>>>(pcs2, pcs1, fArr, gArr); // g-update
  }
  emd_finalize<<<GRID, WGS, 0, stream>>>(pcs1, pcs2, fArr, gArr, partials);
  emd_reduce<<<1, 256, 0, stream>>>(partials, out);
}